// Round 3
// baseline (285.387 us; speedup 1.0000x reference)
//
#include <hip/hip_runtime.h>
#include <stdint.h>

// FrequencySemanticCipher: enc = image + idwt(noise/maxabs), then per-batch min-max norm.
// PRNG: JAX threefry2x32, jax_threefry_partitionable=True semantics.
//
// R2 lesson [counters]: atomics resolve memory-side; give each target its own 64B line.
// R3 lesson [counters]: cooperative fusion loses (grid.sync + occupancy cap).
// R4 lesson [counters]: native v_log_f32 for erfinv's log: k_enc 90->83us. Still 86% VALU.
// R5 (this): k_enc recomputed the SAME 25.2M threefry folds k_minmax already did, plus
//   25.2M erfinvs whose result doesn't depend on the scale. Stage unscaled normal_core
//   floats through `out` (exactly 100.7MB = out size, written at final pixel addresses),
//   so k_enc is just: load noise + img, scale, butterfly, add, store, batch-minmax.
//   VALU work per element now done exactly once across the whole chain.
//
// ws layout (uint32 words), all written-before-read every iteration (graph-replay safe):
// [0 .. 8192)      noise partials: blk*8 + 2*s {bmax_s}, 2*s+1 {~bmin_s}   (1024 blocks)
// [8192 .. 8196)   per-subband scale (float) = sqrt2/(maxabs+eps)
// [8320 + 32*b]    batch mapped min (b<32, init 0xFFFFFFFF by k_scales)
// [8320 + 32*b+16] batch mapped max (init 0)

#define NSUB  6291456u      // 32*3*256*256 quads (= elements per subband)
#define QPT   24            // quads per thread in k_noise
#define NBK   1024          // k_noise blocks = NSUB/(QPT*256)
#define SC    8192
#define BMM   8320
#define NORM_B4 512         // float4s per k_norm block (2 per thread)

struct U2 { uint32_t x, y; };

__host__ __device__ constexpr U2 threefry(uint32_t k0, uint32_t k1, uint32_t x0, uint32_t x1) {
  uint32_t ks2 = k0 ^ k1 ^ 0x1BD11BDAu;
  x0 += k0; x1 += k1;
#define TF_R(r) { x0 += x1; x1 = (x1 << (r)) | (x1 >> (32 - (r))); x1 ^= x0; }
  TF_R(13) TF_R(15) TF_R(26) TF_R(6)
  x0 += k1; x1 += ks2 + 1u;
  TF_R(17) TF_R(29) TF_R(16) TF_R(24)
  x0 += ks2; x1 += k0 + 2u;
  TF_R(13) TF_R(15) TF_R(26) TF_R(6)
  x0 += k0; x1 += k1 + 3u;
  TF_R(17) TF_R(29) TF_R(16) TF_R(24)
  x0 += k1; x1 += ks2 + 4u;
  TF_R(13) TF_R(15) TF_R(26) TF_R(6)
  x0 += ks2; x1 += k0 + 5u;
#undef TF_R
  return U2{x0, x1};
}

// subkey_i = threefry((0,123),(0,i)) — compile-time constants.
constexpr U2 SK0 = threefry(0u, 123u, 0u, 0u);
constexpr U2 SK1 = threefry(0u, 123u, 0u, 1u);
constexpr U2 SK2 = threefry(0u, 123u, 0u, 2u);
constexpr U2 SK3 = threefry(0u, 123u, 0u, 3u);

__device__ __forceinline__ uint32_t tf_fold(uint32_t k0, uint32_t k1, uint32_t x1) {
  U2 r = threefry(k0, k1, 0u, x1);
  return r.x ^ r.y;
}

__device__ __forceinline__ float fast_log2(float x) {
#if __has_builtin(__builtin_amdgcn_logf)
  return __builtin_amdgcn_logf(x);     // v_log_f32: D = log2(S0)
#else
  return __log2f(x);
#endif
}

// erfinv core WITHOUT the sqrt(2) factor (folded into scale). Native-log variant.
__device__ __forceinline__ float normal_core(uint32_t bits) {
  uint32_t fb = (bits >> 9) | 0x3f800000u;
  float f = __uint_as_float(fb) - 1.0f;          // [0,1)
  const float lo = -0.99999994f;
  float u = fmaxf(lo, f * 2.0f + lo);
  float w = -0.69314718056f * fast_log2(1.0f - u * u);   // = -ln(1-u^2)
  float p;
  if (w < 5.0f) {
    w = w - 2.5f;
    p = 2.81022636e-08f;
    p = fmaf(p, w, 3.43273939e-07f);
    p = fmaf(p, w, -3.5233877e-06f);
    p = fmaf(p, w, -4.39150654e-06f);
    p = fmaf(p, w, 0.00021858087f);
    p = fmaf(p, w, -0.00125372503f);
    p = fmaf(p, w, -0.00417768164f);
    p = fmaf(p, w, 0.246640727f);
    p = fmaf(p, w, 1.50140941f);
  } else {
    w = sqrtf(w) - 3.0f;
    p = -0.000200214257f;
    p = fmaf(p, w, 0.000100950558f);
    p = fmaf(p, w, 0.00134934322f);
    p = fmaf(p, w, -0.00367342844f);
    p = fmaf(p, w, 0.00573950773f);
    p = fmaf(p, w, -0.0076224613f);
    p = fmaf(p, w, 0.00943887047f);
    p = fmaf(p, w, 1.00167406f);
    p = fmaf(p, w, 2.83297682f);
  }
  return p * u;
}

// Precise variant (OCML logf, includes sqrt2) for the 4 scale values only.
__device__ __forceinline__ float normal_precise(uint32_t bits) {
  uint32_t fb = (bits >> 9) | 0x3f800000u;
  float f = __uint_as_float(fb) - 1.0f;
  const float lo = -0.99999994f;
  float u = fmaxf(lo, f * 2.0f + lo);
  float w = -logf(1.0f - u * u);
  float p;
  if (w < 5.0f) {
    w = w - 2.5f;
    p = 2.81022636e-08f;
    p = fmaf(p, w, 3.43273939e-07f);
    p = fmaf(p, w, -3.5233877e-06f);
    p = fmaf(p, w, -4.39150654e-06f);
    p = fmaf(p, w, 0.00021858087f);
    p = fmaf(p, w, -0.00125372503f);
    p = fmaf(p, w, -0.00417768164f);
    p = fmaf(p, w, 0.246640727f);
    p = fmaf(p, w, 1.50140941f);
  } else {
    w = sqrtf(w) - 3.0f;
    p = -0.000200214257f;
    p = fmaf(p, w, 0.000100950558f);
    p = fmaf(p, w, 0.00134934322f);
    p = fmaf(p, w, -0.00367342844f);
    p = fmaf(p, w, 0.00573950773f);
    p = fmaf(p, w, -0.0076224613f);
    p = fmaf(p, w, 0.00943887047f);
    p = fmaf(p, w, 1.00167406f);
    p = fmaf(p, w, 2.83297682f);
  }
  return 1.41421354f * p * u;
}

// order-preserving float<->uint map
__device__ __forceinline__ uint32_t map_ord(float f) {
  uint32_t s = __float_as_uint(f);
  return (s & 0x80000000u) ? ~s : (s | 0x80000000u);
}
__device__ __forceinline__ float unmap_ord(uint32_t u) {
  return (u & 0x80000000u) ? __uint_as_float(u ^ 0x80000000u) : __uint_as_float(~u);
}

// K1: per-quad: 4 threefry folds -> (a) per-subband bit min/max partials,
//     (b) unscaled normal_core floats staged into `out` at final pixel addresses.
//     Quad q = ((b*3+c)<<16)|(i<<8)|j; n0,n1 -> row 2i cols 2j,2j+1; n2,n3 -> row 2i+1.
__global__ __launch_bounds__(256) void k_noise(float* __restrict__ out,
                                               uint32_t* __restrict__ ws) {
  const int tid = threadIdx.x;
  const uint32_t q0 = (uint32_t)blockIdx.x * (QPT * 256u) + (uint32_t)tid;
  uint32_t acc[8];   // {bmax_s, ~bmin_s} pairs, reduce-all-with-max
  #pragma unroll
  for (int r = 0; r < 8; r += 2) { acc[r] = 0u; acc[r + 1] = 0u; }
  for (int k = 0; k < QPT; ++k) {
    const uint32_t q = q0 + (uint32_t)k * 256u;
    const uint32_t b0 = tf_fold(SK0.x, SK0.y, q);
    const uint32_t b1 = tf_fold(SK1.x, SK1.y, q);
    const uint32_t b2 = tf_fold(SK2.x, SK2.y, q);
    const uint32_t b3 = tf_fold(SK3.x, SK3.y, q);
    acc[0] = max(acc[0], b0); acc[1] = max(acc[1], ~b0);
    acc[2] = max(acc[2], b1); acc[3] = max(acc[3], ~b1);
    acc[4] = max(acc[4], b2); acc[5] = max(acc[5], ~b2);
    acc[6] = max(acc[6], b3); acc[7] = max(acc[7], ~b3);
    const float n0 = normal_core(b0);
    const float n1 = normal_core(b1);
    const float n2 = normal_core(b2);
    const float n3 = normal_core(b3);
    const uint32_t bc = q >> 16, i = (q >> 8) & 255u, j = q & 255u;
    const size_t base = (size_t)bc * 262144u + (size_t)i * 1024u + 2u * (size_t)j;
    *(float2*)(out + base)       = make_float2(n0, n1);
    *(float2*)(out + base + 512) = make_float2(n2, n3);
  }
  #pragma unroll
  for (int off = 32; off > 0; off >>= 1) {
    #pragma unroll
    for (int r = 0; r < 8; ++r)
      acc[r] = max(acc[r], (uint32_t)__shfl_down(acc[r], off));
  }
  __shared__ uint32_t sU[32];
  const int lane = tid & 63, w = tid >> 6;
  if (lane == 0) {
    #pragma unroll
    for (int r = 0; r < 8; ++r) sU[w * 8 + r] = acc[r];
  }
  __syncthreads();
  if (tid < 8) {
    uint32_t v = max(max(sU[tid], sU[8 + tid]), max(sU[16 + tid], sU[24 + tid]));
    ws[(uint32_t)blockIdx.x * 8u + (uint32_t)tid] = v;
  }
}

// K2: reduce 1024x8 partials -> subband scales; init batch min/max atomic slots.
__global__ void k_scales(uint32_t* __restrict__ ws) {
  const int tid = threadIdx.x;
  const int lane = tid & 63, w = tid >> 6;
  uint32_t v = 0u;
  for (int e = tid >> 3; e < NBK; e += 32)
    v = max(v, ws[(uint32_t)(e * 8) + (uint32_t)(tid & 7)]);   // = ws[tid + 256j], coalesced
  v = max(v, (uint32_t)__shfl_down(v, 32));
  v = max(v, (uint32_t)__shfl_down(v, 16));
  v = max(v, (uint32_t)__shfl_down(v, 8));
  __shared__ uint32_t sU[32];
  if (lane < 8) sU[w * 8 + lane] = v;
  __syncthreads();
  if (tid < 8) {
    uint32_t r = max(max(sU[tid], sU[8 + tid]), max(sU[16 + tid], sU[24 + tid]));
    sU[tid] = r;   // wave-0 lockstep: reads above precede this write per-lane
  }
  __syncthreads();
  if (tid < 4) {
    uint32_t bmax = sU[2 * tid], bmin = ~sU[2 * tid + 1];
    float nmax = normal_precise(bmax);
    float nmin = normal_precise(bmin);
    float mabs = fmaxf(nmax, -nmin);
    ((float*)ws)[SC + tid] = 1.41421354f / (mabs + 1e-8f);   // sqrt2 folded out of core
  }
  if (tid < 32) {
    ws[BMM + 32 * tid]      = 0xFFFFFFFFu;
    ws[BMM + 32 * tid + 16] = 0u;
  }
}

// K3: enc = img + idwt(scaled staged noise); 2 quads/thread, float4 I/O.
//     Reads noise from `out`, writes enc to the SAME addresses (thread-private: safe).
__global__ __launch_bounds__(256) void k_enc(const float* __restrict__ img,
                                             float* __restrict__ out,
                                             uint32_t* __restrict__ ws) {
  const int tid = threadIdx.x;
  const int qi = blockIdx.x * 2 + (tid >> 7);   // quad row 0..255
  const int j2 = tid & 127;                     // quad pair 0..127
  const int bc = blockIdx.z * 3 + blockIdx.y;
  const float* wsf = (const float*)ws;
  const float s0 = wsf[SC + 0], s1 = wsf[SC + 1], s2 = wsf[SC + 2], s3 = wsf[SC + 3];
  const size_t base = ((size_t)bc * 512 + 2 * qi) * 512 + 4 * j2;
  const float4 nt = *(const float4*)(out + base);         // n0,n1 | n0,n1
  const float4 nb = *(const float4*)(out + base + 512);   // n2,n3 | n2,n3
  const float4 it = *(const float4*)(img + base);
  const float4 ib = *(const float4*)(img + base + 512);
  // quad A
  float n0 = nt.x * s0, n1 = nt.y * s1, n2 = nb.x * s2, n3 = nb.y * s3;
  float qa = 0.5f * (n0 + n1 + n2 + n3);
  float qb = 0.5f * (n0 + n1 - n2 - n3);
  float qc = 0.5f * (n0 - n1 + n2 - n3);
  float qd = 0.5f * (n0 - n1 - n2 + n3);
  const float e00 = it.x + qa, e01 = it.y + qb;
  const float e10 = ib.x + qc, e11 = ib.y + qd;
  // quad B
  n0 = nt.z * s0; n1 = nt.w * s1; n2 = nb.z * s2; n3 = nb.w * s3;
  qa = 0.5f * (n0 + n1 + n2 + n3);
  qb = 0.5f * (n0 + n1 - n2 - n3);
  qc = 0.5f * (n0 - n1 + n2 - n3);
  qd = 0.5f * (n0 - n1 - n2 + n3);
  const float f00 = it.z + qa, f01 = it.w + qb;
  const float f10 = ib.z + qc, f11 = ib.w + qd;
  *(float4*)(out + base)       = make_float4(e00, e01, f00, f01);
  *(float4*)(out + base + 512) = make_float4(e10, e11, f10, f11);
  float vmin = fminf(fminf(fminf(e00, e01), fminf(e10, e11)),
                     fminf(fminf(f00, f01), fminf(f10, f11)));
  float vmax = fmaxf(fmaxf(fmaxf(e00, e01), fmaxf(e10, e11)),
                     fmaxf(fmaxf(f00, f01), fmaxf(f10, f11)));
  #pragma unroll
  for (int off = 32; off > 0; off >>= 1) {
    vmin = fminf(vmin, __shfl_down(vmin, off));
    vmax = fmaxf(vmax, __shfl_down(vmax, off));
  }
  __shared__ float smin[4], smax[4];
  const int lane = tid & 63, w = tid >> 6;
  if (lane == 0) { smin[w] = vmin; smax[w] = vmax; }
  __syncthreads();
  if (tid == 0) {
    vmin = fminf(fminf(smin[0], smin[1]), fminf(smin[2], smin[3]));
    vmax = fmaxf(fmaxf(smax[0], smax[1]), fmaxf(smax[2], smax[3]));
    atomicMin(&ws[BMM + 32 * blockIdx.z], map_ord(vmin));
    atomicMax(&ws[BMM + 32 * blockIdx.z + 16], map_ord(vmax));
  }
}

// K4: in-place per-batch min-max normalize; block-uniform batch, 2 float4/thread.
__global__ __launch_bounds__(256) void k_norm(float* __restrict__ out,
                                              const uint32_t* __restrict__ ws) {
  const int bx = blockIdx.x;
  const int b = bx / (196608 / NORM_B4);        // 384 blocks per batch, uniform
  const float mn = unmap_ord(ws[BMM + 32 * b]);
  const float mx = unmap_ord(ws[BMM + 32 * b + 16]);
  const float inv = 1.0f / fmaxf(mx - mn, 1e-8f);
  float4* o4 = (float4*)out;
  const int i0 = bx * NORM_B4 + threadIdx.x;
  float4 v0 = o4[i0];
  float4 v1 = o4[i0 + 256];
  v0.x = (v0.x - mn) * inv; v0.y = (v0.y - mn) * inv;
  v0.z = (v0.z - mn) * inv; v0.w = (v0.w - mn) * inv;
  v1.x = (v1.x - mn) * inv; v1.y = (v1.y - mn) * inv;
  v1.z = (v1.z - mn) * inv; v1.w = (v1.w - mn) * inv;
  o4[i0] = v0;
  o4[i0 + 256] = v1;
}

extern "C" void kernel_launch(void* const* d_in, const int* in_sizes, int n_in,
                              void* d_out, int out_size, void* d_ws, size_t ws_size,
                              hipStream_t stream) {
  const float* img = (const float*)d_in[0];
  float* out = (float*)d_out;
  uint32_t* ws = (uint32_t*)d_ws;

  k_noise<<<NBK, 256, 0, stream>>>(out, ws);
  k_scales<<<1, 256, 0, stream>>>(ws);
  k_enc<<<dim3(128, 3, 32), 256, 0, stream>>>(img, out, ws);
  k_norm<<<NSUB / NORM_B4, 256, 0, stream>>>(out, ws);
}

// Round 4
// 261.307 us; speedup vs baseline: 1.0922x; 1.0922x over previous
//
#include <hip/hip_runtime.h>
#include <stdint.h>

// FrequencySemanticCipher: enc = image + idwt(noise/maxabs), then per-batch min-max norm.
// PRNG: JAX threefry2x32, jax_threefry_partitionable=True semantics.
//
// R2 lesson [counters]: atomics resolve memory-side; give each target its own 64B line.
// R3 lesson [counters]: cooperative fusion loses (grid.sync + occupancy cap).
// R4 lesson [counters]: native v_log_f32 for erfinv: k_enc 90->83us, still 86% VALU.
// R5 lesson [counters]: staging erfinv'd floats unbalances the pipes — k_noise held ALL
//   the VALU (84.6us @ 27% occupancy, writes idle) while k_enc sat mem-bound (~37us,
//   VALU idle). Net regression.
// R6 (this): stage raw BITS instead. K1 = folds only (~30us VALU, 100MB write hidden,
//   2048-block grid fixes the 4-blk/CU occupancy cap). k_enc = erfinv + butterfly
//   overlapped against its own ~37us of L3-resident traffic. The erfinv lives where
//   memory latency needs hiding; folds are computed exactly once.
//
// ws layout (uint32 words), all written-before-read every iteration (graph-replay safe):
// [0 .. 4)        per-subband scale (float) = 0.5*sqrt2/(maxabs+eps)   [0.5 folded in]
// [64 + 32*b]     batch mapped min (b<32, init 0xFFFFFFFF by k_scales)
// [64 + 32*b+16]  batch mapped max (init 0)
// [1088 .. 1088+nbk*8)  K1 partials: blk*8 + 2*s {bmax_s}, 2*s+1 {~bmin_s}
//   nbk=2048 needs 69888B of ws; guarded, falls back to nbk=1024 (37120B <= 40KB floor).

#define NSUB  6291456u      // total quads = 32*3*256*256 (= elements per subband)
#define SC    0
#define BMM   64
#define PART  1088
#define NORM_B4 512         // float4s per k_norm block (2 per thread)

struct U2 { uint32_t x, y; };

__host__ __device__ constexpr U2 threefry(uint32_t k0, uint32_t k1, uint32_t x0, uint32_t x1) {
  uint32_t ks2 = k0 ^ k1 ^ 0x1BD11BDAu;
  x0 += k0; x1 += k1;
#define TF_R(r) { x0 += x1; x1 = (x1 << (r)) | (x1 >> (32 - (r))); x1 ^= x0; }
  TF_R(13) TF_R(15) TF_R(26) TF_R(6)
  x0 += k1; x1 += ks2 + 1u;
  TF_R(17) TF_R(29) TF_R(16) TF_R(24)
  x0 += ks2; x1 += k0 + 2u;
  TF_R(13) TF_R(15) TF_R(26) TF_R(6)
  x0 += k0; x1 += k1 + 3u;
  TF_R(17) TF_R(29) TF_R(16) TF_R(24)
  x0 += k1; x1 += ks2 + 4u;
  TF_R(13) TF_R(15) TF_R(26) TF_R(6)
  x0 += ks2; x1 += k0 + 5u;
#undef TF_R
  return U2{x0, x1};
}

// subkey_i = threefry((0,123),(0,i)) — compile-time constants.
constexpr U2 SK0 = threefry(0u, 123u, 0u, 0u);
constexpr U2 SK1 = threefry(0u, 123u, 0u, 1u);
constexpr U2 SK2 = threefry(0u, 123u, 0u, 2u);
constexpr U2 SK3 = threefry(0u, 123u, 0u, 3u);

__device__ __forceinline__ uint32_t tf_fold(uint32_t k0, uint32_t k1, uint32_t x1) {
  U2 r = threefry(k0, k1, 0u, x1);
  return r.x ^ r.y;
}

__device__ __forceinline__ float fast_log2(float x) {
#if __has_builtin(__builtin_amdgcn_logf)
  return __builtin_amdgcn_logf(x);     // v_log_f32: D = log2(S0)
#else
  return __log2f(x);
#endif
}

// erfinv core WITHOUT the sqrt(2) factor (folded into scale). Native-log variant.
__device__ __forceinline__ float normal_core(uint32_t bits) {
  uint32_t fb = (bits >> 9) | 0x3f800000u;
  float f = __uint_as_float(fb) - 1.0f;          // [0,1)
  const float lo = -0.99999994f;
  float u = fmaxf(lo, f * 2.0f + lo);
  float w = -0.69314718056f * fast_log2(1.0f - u * u);   // = -ln(1-u^2)
  float p;
  if (w < 5.0f) {
    w = w - 2.5f;
    p = 2.81022636e-08f;
    p = fmaf(p, w, 3.43273939e-07f);
    p = fmaf(p, w, -3.5233877e-06f);
    p = fmaf(p, w, -4.39150654e-06f);
    p = fmaf(p, w, 0.00021858087f);
    p = fmaf(p, w, -0.00125372503f);
    p = fmaf(p, w, -0.00417768164f);
    p = fmaf(p, w, 0.246640727f);
    p = fmaf(p, w, 1.50140941f);
  } else {
    w = sqrtf(w) - 3.0f;
    p = -0.000200214257f;
    p = fmaf(p, w, 0.000100950558f);
    p = fmaf(p, w, 0.00134934322f);
    p = fmaf(p, w, -0.00367342844f);
    p = fmaf(p, w, 0.00573950773f);
    p = fmaf(p, w, -0.0076224613f);
    p = fmaf(p, w, 0.00943887047f);
    p = fmaf(p, w, 1.00167406f);
    p = fmaf(p, w, 2.83297682f);
  }
  return p * u;
}

// Precise variant (OCML logf, includes sqrt2) for the 4 scale values only.
__device__ __forceinline__ float normal_precise(uint32_t bits) {
  uint32_t fb = (bits >> 9) | 0x3f800000u;
  float f = __uint_as_float(fb) - 1.0f;
  const float lo = -0.99999994f;
  float u = fmaxf(lo, f * 2.0f + lo);
  float w = -logf(1.0f - u * u);
  float p;
  if (w < 5.0f) {
    w = w - 2.5f;
    p = 2.81022636e-08f;
    p = fmaf(p, w, 3.43273939e-07f);
    p = fmaf(p, w, -3.5233877e-06f);
    p = fmaf(p, w, -4.39150654e-06f);
    p = fmaf(p, w, 0.00021858087f);
    p = fmaf(p, w, -0.00125372503f);
    p = fmaf(p, w, -0.00417768164f);
    p = fmaf(p, w, 0.246640727f);
    p = fmaf(p, w, 1.50140941f);
  } else {
    w = sqrtf(w) - 3.0f;
    p = -0.000200214257f;
    p = fmaf(p, w, 0.000100950558f);
    p = fmaf(p, w, 0.00134934322f);
    p = fmaf(p, w, -0.00367342844f);
    p = fmaf(p, w, 0.00573950773f);
    p = fmaf(p, w, -0.0076224613f);
    p = fmaf(p, w, 0.00943887047f);
    p = fmaf(p, w, 1.00167406f);
    p = fmaf(p, w, 2.83297682f);
  }
  return 1.41421354f * p * u;
}

// order-preserving float<->uint map
__device__ __forceinline__ uint32_t map_ord(float f) {
  uint32_t s = __float_as_uint(f);
  return (s & 0x80000000u) ? ~s : (s | 0x80000000u);
}
__device__ __forceinline__ float unmap_ord(uint32_t u) {
  return (u & 0x80000000u) ? __uint_as_float(u ^ 0x80000000u) : __uint_as_float(~u);
}

// K1: folds only. Per quad q: 4 threefry folds -> (a) per-subband bit-minmax partials,
//     (b) raw bits staged into `out` at the final pixel addresses (b0,b1 -> row 2i,
//     b2,b3 -> row 2i+1). Stored via __uint_as_float (loads/stores are bit-preserving).
__global__ __launch_bounds__(256) void k_bits(float* __restrict__ out,
                                              uint32_t* __restrict__ ws,
                                              int qpt) {
  const int tid = threadIdx.x;
  const uint32_t q0 = (uint32_t)blockIdx.x * ((uint32_t)qpt * 256u) + (uint32_t)tid;
  uint32_t acc[8];   // {bmax_s, ~bmin_s} pairs, reduce-all-with-max
  #pragma unroll
  for (int r = 0; r < 8; ++r) acc[r] = 0u;
  #pragma unroll 4
  for (int k = 0; k < qpt; ++k) {
    const uint32_t q = q0 + (uint32_t)k * 256u;
    const uint32_t b0 = tf_fold(SK0.x, SK0.y, q);
    const uint32_t b1 = tf_fold(SK1.x, SK1.y, q);
    const uint32_t b2 = tf_fold(SK2.x, SK2.y, q);
    const uint32_t b3 = tf_fold(SK3.x, SK3.y, q);
    acc[0] = max(acc[0], b0); acc[1] = max(acc[1], ~b0);
    acc[2] = max(acc[2], b1); acc[3] = max(acc[3], ~b1);
    acc[4] = max(acc[4], b2); acc[5] = max(acc[5], ~b2);
    acc[6] = max(acc[6], b3); acc[7] = max(acc[7], ~b3);
    // base = (q>>8)*1024 + 2*(q&255)  [= bc*262144 + i*1024 + 2j]
    const size_t base = (size_t)(q >> 8) * 1024u + 2u * (size_t)(q & 255u);
    *(float2*)(out + base)       = make_float2(__uint_as_float(b0), __uint_as_float(b1));
    *(float2*)(out + base + 512) = make_float2(__uint_as_float(b2), __uint_as_float(b3));
  }
  #pragma unroll
  for (int off = 32; off > 0; off >>= 1) {
    #pragma unroll
    for (int r = 0; r < 8; ++r)
      acc[r] = max(acc[r], (uint32_t)__shfl_down(acc[r], off));
  }
  __shared__ uint32_t sU[32];
  const int lane = tid & 63, w = tid >> 6;
  if (lane == 0) {
    #pragma unroll
    for (int r = 0; r < 8; ++r) sU[w * 8 + r] = acc[r];
  }
  __syncthreads();
  if (tid < 8) {
    uint32_t v = max(max(sU[tid], sU[8 + tid]), max(sU[16 + tid], sU[24 + tid]));
    ws[PART + (uint32_t)blockIdx.x * 8u + (uint32_t)tid] = v;
  }
}

// K2: reduce nbk x 8 partials -> subband scales (0.5 folded in); init batch slots.
__global__ void k_scales(uint32_t* __restrict__ ws, int nbk) {
  const int tid = threadIdx.x;
  const int lane = tid & 63, w = tid >> 6;
  uint32_t v = 0u;
  for (int e = tid >> 3; e < nbk; e += 32)
    v = max(v, ws[PART + (uint32_t)(e * 8) + (uint32_t)(tid & 7)]);   // coalesced
  v = max(v, (uint32_t)__shfl_down(v, 32));
  v = max(v, (uint32_t)__shfl_down(v, 16));
  v = max(v, (uint32_t)__shfl_down(v, 8));
  __shared__ uint32_t sU[32];
  if (lane < 8) sU[w * 8 + lane] = v;
  __syncthreads();
  if (tid < 8) {
    uint32_t r = max(max(sU[tid], sU[8 + tid]), max(sU[16 + tid], sU[24 + tid]));
    sU[tid] = r;   // wave-0 lockstep: reads above precede this write per-lane
  }
  __syncthreads();
  if (tid < 4) {
    uint32_t bmax = sU[2 * tid], bmin = ~sU[2 * tid + 1];
    float nmax = normal_precise(bmax);
    float nmin = normal_precise(bmin);
    float mabs = fmaxf(nmax, -nmin);
    // 0.5 (idwt) and sqrt2 (normal_core omits it) folded into the scale; both exact-ish:
    // 0.5 multiply is exact, so butterfly sums stay bit-identical to the 0.5f*(...) form.
    ((float*)ws)[SC + tid] = 0.5f * (1.41421354f / (mabs + 1e-8f));
  }
  if (tid < 32) {
    ws[BMM + 32 * tid]      = 0xFFFFFFFFu;
    ws[BMM + 32 * tid + 16] = 0u;
  }
}

// K3: enc = img + idwt(scaled erfinv(bits)); 2 quads/thread, float4 I/O.
//     Reads staged bits from `out` (as float4 + __float_as_uint: same-type accesses,
//     no TBAA reorder hazard), writes enc to the SAME addresses (thread-private: safe).
__global__ __launch_bounds__(256) void k_enc(const float* __restrict__ img,
                                             float* __restrict__ out,
                                             uint32_t* __restrict__ ws) {
  const int tid = threadIdx.x;
  const int qi = blockIdx.x * 2 + (tid >> 7);   // quad row 0..255
  const int j2 = tid & 127;                     // quad pair 0..127
  const int bc = blockIdx.z * 3 + blockIdx.y;
  const float* wsf = (const float*)ws;
  const float s0 = wsf[SC + 0], s1 = wsf[SC + 1], s2 = wsf[SC + 2], s3 = wsf[SC + 3];
  const size_t base = ((size_t)bc * 512 + 2 * qi) * 512 + 4 * j2;
  const float4 bt = *(const float4*)(out + base);         // bits b0,b1 | b0,b1
  const float4 bb = *(const float4*)(out + base + 512);   // bits b2,b3 | b2,b3
  const float4 it = *(const float4*)(img + base);
  const float4 ib = *(const float4*)(img + base + 512);
  // quad A  (n_s pre-scaled by 0.5*scale_s — butterfly sums bit-identical to 0.5f*(...))
  float n0 = normal_core(__float_as_uint(bt.x)) * s0;
  float n1 = normal_core(__float_as_uint(bt.y)) * s1;
  float n2 = normal_core(__float_as_uint(bb.x)) * s2;
  float n3 = normal_core(__float_as_uint(bb.y)) * s3;
  float qa = n0 + n1 + n2 + n3;
  float qb = n0 + n1 - n2 - n3;
  float qc = n0 - n1 + n2 - n3;
  float qd = n0 - n1 - n2 + n3;
  const float e00 = it.x + qa, e01 = it.y + qb;
  const float e10 = ib.x + qc, e11 = ib.y + qd;
  // quad B
  n0 = normal_core(__float_as_uint(bt.z)) * s0;
  n1 = normal_core(__float_as_uint(bt.w)) * s1;
  n2 = normal_core(__float_as_uint(bb.z)) * s2;
  n3 = normal_core(__float_as_uint(bb.w)) * s3;
  qa = n0 + n1 + n2 + n3;
  qb = n0 + n1 - n2 - n3;
  qc = n0 - n1 + n2 - n3;
  qd = n0 - n1 - n2 + n3;
  const float f00 = it.z + qa, f01 = it.w + qb;
  const float f10 = ib.z + qc, f11 = ib.w + qd;
  *(float4*)(out + base)       = make_float4(e00, e01, f00, f01);
  *(float4*)(out + base + 512) = make_float4(e10, e11, f10, f11);
  float vmin = fminf(fminf(fminf(e00, e01), fminf(e10, e11)),
                     fminf(fminf(f00, f01), fminf(f10, f11)));
  float vmax = fmaxf(fmaxf(fmaxf(e00, e01), fmaxf(e10, e11)),
                     fmaxf(fmaxf(f00, f01), fmaxf(f10, f11)));
  #pragma unroll
  for (int off = 32; off > 0; off >>= 1) {
    vmin = fminf(vmin, __shfl_down(vmin, off));
    vmax = fmaxf(vmax, __shfl_down(vmax, off));
  }
  __shared__ float smin[4], smax[4];
  const int lane = tid & 63, w = tid >> 6;
  if (lane == 0) { smin[w] = vmin; smax[w] = vmax; }
  __syncthreads();
  if (tid == 0) {
    vmin = fminf(fminf(smin[0], smin[1]), fminf(smin[2], smin[3]));
    vmax = fmaxf(fmaxf(smax[0], smax[1]), fmaxf(smax[2], smax[3]));
    atomicMin(&ws[BMM + 32 * blockIdx.z], map_ord(vmin));
    atomicMax(&ws[BMM + 32 * blockIdx.z + 16], map_ord(vmax));
  }
}

// K4: in-place per-batch min-max normalize; block-uniform batch, 2 float4/thread.
__global__ __launch_bounds__(256) void k_norm(float* __restrict__ out,
                                              const uint32_t* __restrict__ ws) {
  const int bx = blockIdx.x;
  const int b = bx / (196608 / NORM_B4);        // 384 blocks per batch, uniform
  const float mn = unmap_ord(ws[BMM + 32 * b]);
  const float mx = unmap_ord(ws[BMM + 32 * b + 16]);
  const float inv = 1.0f / fmaxf(mx - mn, 1e-8f);
  float4* o4 = (float4*)out;
  const int i0 = bx * NORM_B4 + threadIdx.x;
  float4 v0 = o4[i0];
  float4 v1 = o4[i0 + 256];
  v0.x = (v0.x - mn) * inv; v0.y = (v0.y - mn) * inv;
  v0.z = (v0.z - mn) * inv; v0.w = (v0.w - mn) * inv;
  v1.x = (v1.x - mn) * inv; v1.y = (v1.y - mn) * inv;
  v1.z = (v1.z - mn) * inv; v1.w = (v1.w - mn) * inv;
  o4[i0] = v0;
  o4[i0 + 256] = v1;
}

extern "C" void kernel_launch(void* const* d_in, const int* in_sizes, int n_in,
                              void* d_out, int out_size, void* d_ws, size_t ws_size,
                              hipStream_t stream) {
  const float* img = (const float*)d_in[0];
  float* out = (float*)d_out;
  uint32_t* ws = (uint32_t*)d_ws;

  // 2048 blocks (8/CU, fixes R5's occupancy cap) needs 69888B of ws; else 1024 (37120B).
  const int nbk = (ws_size >= (size_t)(PART + 2048 * 8) * 4u) ? 2048 : 1024;
  const int qpt = (int)(NSUB / (256u * (uint32_t)nbk));

  k_bits<<<nbk, 256, 0, stream>>>(out, ws, qpt);
  k_scales<<<1, 256, 0, stream>>>(ws, nbk);
  k_enc<<<dim3(128, 3, 32), 256, 0, stream>>>(img, out, ws);
  k_norm<<<NSUB / NORM_B4, 256, 0, stream>>>(out, ws);
}

// Round 5
// 256.579 us; speedup vs baseline: 1.1123x; 1.0184x over previous
//
#include <hip/hip_runtime.h>
#include <stdint.h>

// FrequencySemanticCipher: enc = image + idwt(noise/maxabs), then per-batch min-max norm.
// PRNG: JAX threefry2x32, jax_threefry_partitionable=True semantics.
//
// R2 lesson [counters]: atomics resolve memory-side; give each target its own 64B line.
// R3 lesson [counters]: cooperative fusion loses (grid.sync + occupancy cap).
// R4 lesson [counters]: native v_log_f32 for erfinv: k_enc 90->83us, still 86% VALU.
// R5 lesson [counters]: staging erfinv'd floats unbalances pipes (VALU-heavy pass sat
//   at low occupancy while k_enc went mem-bound idle). Stage raw BITS instead.
// R6 lesson [counters]: bits-staging chain = 261us; top-5 now all harness fillBuffer
//   (60us @ 85% HBM peak, per-iteration poison — fixed cost). Chain ~125us.
// R7 (this): remove the k_scales serialization bubble. k_bits -> 8 global atomicMax
//   slots (8 distinct 64B lines; ~22ns arrival vs 11ns service per line: no queue);
//   k_enc derives the 4 scales per-block in a 4-thread preamble. Tiny k_init zeroes
//   the slots (poison-robust). k_bits: 2 quads/thread -> float4 stores (half the
//   store-issue slots), strength-reduced addressing.
//
// ws layout (uint32 words), all written-before-read every iteration (graph-replay safe):
// [16*r], r<8      subband atomic slots: r=2s -> bmax_s, r=2s+1 -> ~bmin_s (init 0)
// [128 + 32*b]     batch mapped min (b<32, init 0xFFFFFFFF)
// [128 + 32*b+16]  batch mapped max (init 0)

#define NSUB  6291456u      // total quads = 32*3*256*256 (= elements per subband)
#define SBM   0
#define BMM   128
#define NBK   2048          // k_bits blocks (8/CU target)
#define PPT   6             // quad-PAIRS per thread in k_bits: 2048*256*6*2 = NSUB
#define NORM_B4 512         // float4s per k_norm block (2 per thread)

struct U2 { uint32_t x, y; };

__host__ __device__ constexpr U2 threefry(uint32_t k0, uint32_t k1, uint32_t x0, uint32_t x1) {
  uint32_t ks2 = k0 ^ k1 ^ 0x1BD11BDAu;
  x0 += k0; x1 += k1;
#define TF_R(r) { x0 += x1; x1 = (x1 << (r)) | (x1 >> (32 - (r))); x1 ^= x0; }
  TF_R(13) TF_R(15) TF_R(26) TF_R(6)
  x0 += k1; x1 += ks2 + 1u;
  TF_R(17) TF_R(29) TF_R(16) TF_R(24)
  x0 += ks2; x1 += k0 + 2u;
  TF_R(13) TF_R(15) TF_R(26) TF_R(6)
  x0 += k0; x1 += k1 + 3u;
  TF_R(17) TF_R(29) TF_R(16) TF_R(24)
  x0 += k1; x1 += ks2 + 4u;
  TF_R(13) TF_R(15) TF_R(26) TF_R(6)
  x0 += ks2; x1 += k0 + 5u;
#undef TF_R
  return U2{x0, x1};
}

// subkey_i = threefry((0,123),(0,i)) — compile-time constants.
constexpr U2 SK0 = threefry(0u, 123u, 0u, 0u);
constexpr U2 SK1 = threefry(0u, 123u, 0u, 1u);
constexpr U2 SK2 = threefry(0u, 123u, 0u, 2u);
constexpr U2 SK3 = threefry(0u, 123u, 0u, 3u);

__device__ __forceinline__ uint32_t tf_fold(uint32_t k0, uint32_t k1, uint32_t x1) {
  U2 r = threefry(k0, k1, 0u, x1);
  return r.x ^ r.y;
}

__device__ __forceinline__ float fast_log2(float x) {
#if __has_builtin(__builtin_amdgcn_logf)
  return __builtin_amdgcn_logf(x);     // v_log_f32: D = log2(S0)
#else
  return __log2f(x);
#endif
}

// erfinv core WITHOUT the sqrt(2) factor (folded into scale). Native-log variant.
__device__ __forceinline__ float normal_core(uint32_t bits) {
  uint32_t fb = (bits >> 9) | 0x3f800000u;
  float f = __uint_as_float(fb) - 1.0f;          // [0,1)
  const float lo = -0.99999994f;
  float u = fmaxf(lo, f * 2.0f + lo);
  float w = -0.69314718056f * fast_log2(1.0f - u * u);   // = -ln(1-u^2)
  float p;
  if (w < 5.0f) {
    w = w - 2.5f;
    p = 2.81022636e-08f;
    p = fmaf(p, w, 3.43273939e-07f);
    p = fmaf(p, w, -3.5233877e-06f);
    p = fmaf(p, w, -4.39150654e-06f);
    p = fmaf(p, w, 0.00021858087f);
    p = fmaf(p, w, -0.00125372503f);
    p = fmaf(p, w, -0.00417768164f);
    p = fmaf(p, w, 0.246640727f);
    p = fmaf(p, w, 1.50140941f);
  } else {
    w = sqrtf(w) - 3.0f;
    p = -0.000200214257f;
    p = fmaf(p, w, 0.000100950558f);
    p = fmaf(p, w, 0.00134934322f);
    p = fmaf(p, w, -0.00367342844f);
    p = fmaf(p, w, 0.00573950773f);
    p = fmaf(p, w, -0.0076224613f);
    p = fmaf(p, w, 0.00943887047f);
    p = fmaf(p, w, 1.00167406f);
    p = fmaf(p, w, 2.83297682f);
  }
  return p * u;
}

// Precise variant (OCML logf, includes sqrt2) for the 4 scale values only.
__device__ __forceinline__ float normal_precise(uint32_t bits) {
  uint32_t fb = (bits >> 9) | 0x3f800000u;
  float f = __uint_as_float(fb) - 1.0f;
  const float lo = -0.99999994f;
  float u = fmaxf(lo, f * 2.0f + lo);
  float w = -logf(1.0f - u * u);
  float p;
  if (w < 5.0f) {
    w = w - 2.5f;
    p = 2.81022636e-08f;
    p = fmaf(p, w, 3.43273939e-07f);
    p = fmaf(p, w, -3.5233877e-06f);
    p = fmaf(p, w, -4.39150654e-06f);
    p = fmaf(p, w, 0.00021858087f);
    p = fmaf(p, w, -0.00125372503f);
    p = fmaf(p, w, -0.00417768164f);
    p = fmaf(p, w, 0.246640727f);
    p = fmaf(p, w, 1.50140941f);
  } else {
    w = sqrtf(w) - 3.0f;
    p = -0.000200214257f;
    p = fmaf(p, w, 0.000100950558f);
    p = fmaf(p, w, 0.00134934322f);
    p = fmaf(p, w, -0.00367342844f);
    p = fmaf(p, w, 0.00573950773f);
    p = fmaf(p, w, -0.0076224613f);
    p = fmaf(p, w, 0.00943887047f);
    p = fmaf(p, w, 1.00167406f);
    p = fmaf(p, w, 2.83297682f);
  }
  return 1.41421354f * p * u;
}

// order-preserving float<->uint map
__device__ __forceinline__ uint32_t map_ord(float f) {
  uint32_t s = __float_as_uint(f);
  return (s & 0x80000000u) ? ~s : (s | 0x80000000u);
}
__device__ __forceinline__ float unmap_ord(uint32_t u) {
  return (u & 0x80000000u) ? __uint_as_float(u ^ 0x80000000u) : __uint_as_float(~u);
}

// K0: init the 8 subband atomic slots + 64 batch slots (poison-robust, ~1.5us).
__global__ void k_init(uint32_t* __restrict__ ws) {
  const int t = threadIdx.x;
  if (t < 8) ws[SBM + 16 * t] = 0u;
  if (t < 32) {
    ws[BMM + 32 * t]      = 0xFFFFFFFFu;
    ws[BMM + 32 * t + 16] = 0u;
  }
}

// K1: folds only. Per quad-pair p (quads 2p, 2p+1: same row, adjacent cols):
//     8 threefry folds -> (a) per-subband bit-minmax acc, (b) raw bits staged into
//     `out` as two float4 stores at the final pixel addresses.
//     Block tail: 8 atomicMax to dedicated 64B lines (no k_scales pass needed).
__global__ __launch_bounds__(256) void k_bits(float* __restrict__ out,
                                              uint32_t* __restrict__ ws) {
  const int tid = threadIdx.x;
  uint32_t p = (uint32_t)blockIdx.x * (PPT * 256u) + (uint32_t)tid;
  size_t base = (size_t)(p >> 7) * 1024u + 4u * (size_t)(p & 127u);
  uint32_t acc[8];   // {bmax_s, ~bmin_s} pairs, reduce-all-with-max
  #pragma unroll
  for (int r = 0; r < 8; ++r) acc[r] = 0u;
  #pragma unroll 2
  for (int k = 0; k < PPT; ++k) {
    const uint32_t qa = 2u * p, qb = 2u * p + 1u;
    const uint32_t a0 = tf_fold(SK0.x, SK0.y, qa);
    const uint32_t a1 = tf_fold(SK1.x, SK1.y, qa);
    const uint32_t a2 = tf_fold(SK2.x, SK2.y, qa);
    const uint32_t a3 = tf_fold(SK3.x, SK3.y, qa);
    const uint32_t b0 = tf_fold(SK0.x, SK0.y, qb);
    const uint32_t b1 = tf_fold(SK1.x, SK1.y, qb);
    const uint32_t b2 = tf_fold(SK2.x, SK2.y, qb);
    const uint32_t b3 = tf_fold(SK3.x, SK3.y, qb);
    acc[0] = max(acc[0], max(a0, b0)); acc[1] = max(acc[1], max(~a0, ~b0));
    acc[2] = max(acc[2], max(a1, b1)); acc[3] = max(acc[3], max(~a1, ~b1));
    acc[4] = max(acc[4], max(a2, b2)); acc[5] = max(acc[5], max(~a2, ~b2));
    acc[6] = max(acc[6], max(a3, b3)); acc[7] = max(acc[7], max(~a3, ~b3));
    // row 2i: (a0,a1 | b0,b1); row 2i+1: (a2,a3 | b2,b3)
    *(float4*)(out + base) = make_float4(__uint_as_float(a0), __uint_as_float(a1),
                                         __uint_as_float(b0), __uint_as_float(b1));
    *(float4*)(out + base + 512) = make_float4(__uint_as_float(a2), __uint_as_float(a3),
                                               __uint_as_float(b2), __uint_as_float(b3));
    p += 256u;        // strength-reduced: row += 2 per step
    base += 2048u;
  }
  #pragma unroll
  for (int off = 32; off > 0; off >>= 1) {
    #pragma unroll
    for (int r = 0; r < 8; ++r)
      acc[r] = max(acc[r], (uint32_t)__shfl_down(acc[r], off));
  }
  __shared__ uint32_t sU[32];
  const int lane = tid & 63, w = tid >> 6;
  if (lane == 0) {
    #pragma unroll
    for (int r = 0; r < 8; ++r) sU[w * 8 + r] = acc[r];
  }
  __syncthreads();
  if (tid < 8) {
    uint32_t v = max(max(sU[tid], sU[8 + tid]), max(sU[16 + tid], sU[24 + tid]));
    atomicMax(&ws[SBM + 16 * tid], v);
  }
}

// K2: enc = img + idwt(scaled erfinv(bits)); 2 quads/thread, float4 I/O.
//     4-thread preamble derives the subband scales from the 8 atomic words
//     (deterministic, identical in every block). Reads staged bits from `out`,
//     writes enc to the SAME addresses (thread-private: safe).
__global__ __launch_bounds__(256) void k_enc(const float* __restrict__ img,
                                             float* __restrict__ out,
                                             uint32_t* __restrict__ ws) {
  const int tid = threadIdx.x;
  __shared__ float sSc[4];
  if (tid < 4) {
    const uint32_t bmax = ws[SBM + 16 * (2 * tid)];
    const uint32_t bmin = ~ws[SBM + 16 * (2 * tid + 1)];
    const float nmax = normal_precise(bmax);
    const float nmin = normal_precise(bmin);
    const float mabs = fmaxf(nmax, -nmin);
    // 0.5 (idwt) and sqrt2 (normal_core omits it) folded in; 0.5 mult is exact.
    sSc[tid] = 0.5f * (1.41421354f / (mabs + 1e-8f));
  }
  __syncthreads();
  const float s0 = sSc[0], s1 = sSc[1], s2 = sSc[2], s3 = sSc[3];

  const int qi = blockIdx.x * 2 + (tid >> 7);   // quad row 0..255
  const int j2 = tid & 127;                     // quad pair 0..127
  const int bc = blockIdx.z * 3 + blockIdx.y;
  const size_t base = ((size_t)bc * 512 + 2 * qi) * 512 + 4 * j2;
  const float4 bt = *(const float4*)(out + base);         // bits a0,a1 | b0,b1
  const float4 bb = *(const float4*)(out + base + 512);   // bits a2,a3 | b2,b3
  const float4 it = *(const float4*)(img + base);
  const float4 ib = *(const float4*)(img + base + 512);
  // quad A  (n_s pre-scaled by 0.5*scale_s — butterfly sums bit-identical to 0.5f*(...))
  float n0 = normal_core(__float_as_uint(bt.x)) * s0;
  float n1 = normal_core(__float_as_uint(bt.y)) * s1;
  float n2 = normal_core(__float_as_uint(bb.x)) * s2;
  float n3 = normal_core(__float_as_uint(bb.y)) * s3;
  float qa = n0 + n1 + n2 + n3;
  float qb = n0 + n1 - n2 - n3;
  float qc = n0 - n1 + n2 - n3;
  float qd = n0 - n1 - n2 + n3;
  const float e00 = it.x + qa, e01 = it.y + qb;
  const float e10 = ib.x + qc, e11 = ib.y + qd;
  // quad B
  n0 = normal_core(__float_as_uint(bt.z)) * s0;
  n1 = normal_core(__float_as_uint(bt.w)) * s1;
  n2 = normal_core(__float_as_uint(bb.z)) * s2;
  n3 = normal_core(__float_as_uint(bb.w)) * s3;
  qa = n0 + n1 + n2 + n3;
  qb = n0 + n1 - n2 - n3;
  qc = n0 - n1 + n2 - n3;
  qd = n0 - n1 - n2 + n3;
  const float f00 = it.z + qa, f01 = it.w + qb;
  const float f10 = ib.z + qc, f11 = ib.w + qd;
  *(float4*)(out + base)       = make_float4(e00, e01, f00, f01);
  *(float4*)(out + base + 512) = make_float4(e10, e11, f10, f11);
  float vmin = fminf(fminf(fminf(e00, e01), fminf(e10, e11)),
                     fminf(fminf(f00, f01), fminf(f10, f11)));
  float vmax = fmaxf(fmaxf(fmaxf(e00, e01), fmaxf(e10, e11)),
                     fmaxf(fmaxf(f00, f01), fmaxf(f10, f11)));
  #pragma unroll
  for (int off = 32; off > 0; off >>= 1) {
    vmin = fminf(vmin, __shfl_down(vmin, off));
    vmax = fmaxf(vmax, __shfl_down(vmax, off));
  }
  __shared__ float smin[4], smax[4];
  const int lane = tid & 63, w = tid >> 6;
  if (lane == 0) { smin[w] = vmin; smax[w] = vmax; }
  __syncthreads();
  if (tid == 0) {
    vmin = fminf(fminf(smin[0], smin[1]), fminf(smin[2], smin[3]));
    vmax = fmaxf(fmaxf(smax[0], smax[1]), fmaxf(smax[2], smax[3]));
    atomicMin(&ws[BMM + 32 * blockIdx.z], map_ord(vmin));
    atomicMax(&ws[BMM + 32 * blockIdx.z + 16], map_ord(vmax));
  }
}

// K3: in-place per-batch min-max normalize; block-uniform batch, 2 float4/thread.
__global__ __launch_bounds__(256) void k_norm(float* __restrict__ out,
                                              const uint32_t* __restrict__ ws) {
  const int bx = blockIdx.x;
  const int b = bx / (196608 / NORM_B4);        // 384 blocks per batch, uniform
  const float mn = unmap_ord(ws[BMM + 32 * b]);
  const float mx = unmap_ord(ws[BMM + 32 * b + 16]);
  const float inv = 1.0f / fmaxf(mx - mn, 1e-8f);
  float4* o4 = (float4*)out;
  const int i0 = bx * NORM_B4 + threadIdx.x;
  float4 v0 = o4[i0];
  float4 v1 = o4[i0 + 256];
  v0.x = (v0.x - mn) * inv; v0.y = (v0.y - mn) * inv;
  v0.z = (v0.z - mn) * inv; v0.w = (v0.w - mn) * inv;
  v1.x = (v1.x - mn) * inv; v1.y = (v1.y - mn) * inv;
  v1.z = (v1.z - mn) * inv; v1.w = (v1.w - mn) * inv;
  o4[i0] = v0;
  o4[i0 + 256] = v1;
}

extern "C" void kernel_launch(void* const* d_in, const int* in_sizes, int n_in,
                              void* d_out, int out_size, void* d_ws, size_t ws_size,
                              hipStream_t stream) {
  const float* img = (const float*)d_in[0];
  float* out = (float*)d_out;
  uint32_t* ws = (uint32_t*)d_ws;

  k_init<<<1, 64, 0, stream>>>(ws);
  k_bits<<<NBK, 256, 0, stream>>>(out, ws);
  k_enc<<<dim3(128, 3, 32), 256, 0, stream>>>(img, out, ws);
  k_norm<<<NSUB / NORM_B4, 256, 0, stream>>>(out, ws);
}

// Round 6
// 251.286 us; speedup vs baseline: 1.1357x; 1.0211x over previous
//
#include <hip/hip_runtime.h>
#include <stdint.h>

// FrequencySemanticCipher: enc = image + idwt(noise/maxabs), then per-batch min-max norm.
// PRNG: JAX threefry2x32, jax_threefry_partitionable=True semantics.
//
// R2 lesson [counters]: atomics resolve memory-side; give each target its own 64B line.
// R3 lesson [counters]: cooperative fusion loses (grid.sync + occupancy cap).
// R4 lesson [counters]: native v_log_f32 for erfinv: k_enc 90->83us, still 86% VALU.
// R5 lesson [counters]: staging erfinv'd floats unbalances pipes. Stage raw BITS.
// R6 lesson [counters]: bits-staging chain = 261us; top-5 all harness fillBuffer
//   (60us @ 85% HBM peak, per-iteration poison — fixed cost).
// R7 lesson [counters]: k_enc 60.6us @ VALU 43% / 3.3TB/s — overlap-bound, not pipe-
//   bound. Culprits: per-block scale preamble (serialized logf + barrier gating all
//   4 waves, ~48x/CU) and only 4 outstanding loads/thread.
// R8 (this): (1) scales computed by k_bits' LAST block (atomic ticket; __syncthreads
//   drains vmcnt so all atomicMax are globally performed before tickets) -> k_enc
//   preamble = 4 uniform loads, zero barriers. (2) k_enc 4 quads/thread, all 8
//   float4 loads issued up front. (3) k_norm 4 float4/thread.
//
// ws layout (uint32 words), all written-before-read every iteration (graph-replay safe):
// [16*r], r<8      subband atomic slots: r=2s -> bmax_s, r=2s+1 -> ~bmin_s (init 0)
// [128]            k_bits completion counter (init 0, own 64B line)
// [144 .. 148)     per-subband scale (float) = 0.5*sqrt2/(maxabs+eps)  (own line)
// [192 + 32*b]     batch mapped min (b<32, init 0xFFFFFFFF)
// [192 + 32*b+16]  batch mapped max (init 0)

#define NSUB  6291456u      // total quads = 32*3*256*256 (= elements per subband)
#define SBM   0
#define CNT   128
#define SC    144
#define BMM   192
#define NBK   2048          // k_bits blocks (8/CU target)
#define PPT   6             // quad-PAIRS per thread in k_bits: 2048*256*6*2 = NSUB
#define NORM_B4 1024        // float4s per k_norm block (4 per thread)

struct U2 { uint32_t x, y; };

__host__ __device__ constexpr U2 threefry(uint32_t k0, uint32_t k1, uint32_t x0, uint32_t x1) {
  uint32_t ks2 = k0 ^ k1 ^ 0x1BD11BDAu;
  x0 += k0; x1 += k1;
#define TF_R(r) { x0 += x1; x1 = (x1 << (r)) | (x1 >> (32 - (r))); x1 ^= x0; }
  TF_R(13) TF_R(15) TF_R(26) TF_R(6)
  x0 += k1; x1 += ks2 + 1u;
  TF_R(17) TF_R(29) TF_R(16) TF_R(24)
  x0 += ks2; x1 += k0 + 2u;
  TF_R(13) TF_R(15) TF_R(26) TF_R(6)
  x0 += k0; x1 += k1 + 3u;
  TF_R(17) TF_R(29) TF_R(16) TF_R(24)
  x0 += k1; x1 += ks2 + 4u;
  TF_R(13) TF_R(15) TF_R(26) TF_R(6)
  x0 += ks2; x1 += k0 + 5u;
#undef TF_R
  return U2{x0, x1};
}

// subkey_i = threefry((0,123),(0,i)) — compile-time constants.
constexpr U2 SK0 = threefry(0u, 123u, 0u, 0u);
constexpr U2 SK1 = threefry(0u, 123u, 0u, 1u);
constexpr U2 SK2 = threefry(0u, 123u, 0u, 2u);
constexpr U2 SK3 = threefry(0u, 123u, 0u, 3u);

__device__ __forceinline__ uint32_t tf_fold(uint32_t k0, uint32_t k1, uint32_t x1) {
  U2 r = threefry(k0, k1, 0u, x1);
  return r.x ^ r.y;
}

__device__ __forceinline__ float fast_log2(float x) {
#if __has_builtin(__builtin_amdgcn_logf)
  return __builtin_amdgcn_logf(x);     // v_log_f32: D = log2(S0)
#else
  return __log2f(x);
#endif
}

// erfinv core WITHOUT the sqrt(2) factor (folded into scale). Native-log variant.
__device__ __forceinline__ float normal_core(uint32_t bits) {
  uint32_t fb = (bits >> 9) | 0x3f800000u;
  float f = __uint_as_float(fb) - 1.0f;          // [0,1)
  const float lo = -0.99999994f;
  float u = fmaxf(lo, f * 2.0f + lo);
  float w = -0.69314718056f * fast_log2(1.0f - u * u);   // = -ln(1-u^2)
  float p;
  if (w < 5.0f) {
    w = w - 2.5f;
    p = 2.81022636e-08f;
    p = fmaf(p, w, 3.43273939e-07f);
    p = fmaf(p, w, -3.5233877e-06f);
    p = fmaf(p, w, -4.39150654e-06f);
    p = fmaf(p, w, 0.00021858087f);
    p = fmaf(p, w, -0.00125372503f);
    p = fmaf(p, w, -0.00417768164f);
    p = fmaf(p, w, 0.246640727f);
    p = fmaf(p, w, 1.50140941f);
  } else {
    w = sqrtf(w) - 3.0f;
    p = -0.000200214257f;
    p = fmaf(p, w, 0.000100950558f);
    p = fmaf(p, w, 0.00134934322f);
    p = fmaf(p, w, -0.00367342844f);
    p = fmaf(p, w, 0.00573950773f);
    p = fmaf(p, w, -0.0076224613f);
    p = fmaf(p, w, 0.00943887047f);
    p = fmaf(p, w, 1.00167406f);
    p = fmaf(p, w, 2.83297682f);
  }
  return p * u;
}

// Precise variant (OCML logf, includes sqrt2) for the 4 scale values only.
__device__ __forceinline__ float normal_precise(uint32_t bits) {
  uint32_t fb = (bits >> 9) | 0x3f800000u;
  float f = __uint_as_float(fb) - 1.0f;
  const float lo = -0.99999994f;
  float u = fmaxf(lo, f * 2.0f + lo);
  float w = -logf(1.0f - u * u);
  float p;
  if (w < 5.0f) {
    w = w - 2.5f;
    p = 2.81022636e-08f;
    p = fmaf(p, w, 3.43273939e-07f);
    p = fmaf(p, w, -3.5233877e-06f);
    p = fmaf(p, w, -4.39150654e-06f);
    p = fmaf(p, w, 0.00021858087f);
    p = fmaf(p, w, -0.00125372503f);
    p = fmaf(p, w, -0.00417768164f);
    p = fmaf(p, w, 0.246640727f);
    p = fmaf(p, w, 1.50140941f);
  } else {
    w = sqrtf(w) - 3.0f;
    p = -0.000200214257f;
    p = fmaf(p, w, 0.000100950558f);
    p = fmaf(p, w, 0.00134934322f);
    p = fmaf(p, w, -0.00367342844f);
    p = fmaf(p, w, 0.00573950773f);
    p = fmaf(p, w, -0.0076224613f);
    p = fmaf(p, w, 0.00943887047f);
    p = fmaf(p, w, 1.00167406f);
    p = fmaf(p, w, 2.83297682f);
  }
  return 1.41421354f * p * u;
}

// order-preserving float<->uint map
__device__ __forceinline__ uint32_t map_ord(float f) {
  uint32_t s = __float_as_uint(f);
  return (s & 0x80000000u) ? ~s : (s | 0x80000000u);
}
__device__ __forceinline__ float unmap_ord(uint32_t u) {
  return (u & 0x80000000u) ? __uint_as_float(u ^ 0x80000000u) : __uint_as_float(~u);
}

// K0: init subband slots, ticket counter, batch slots (poison-robust, ~1.5us).
__global__ void k_init(uint32_t* __restrict__ ws) {
  const int t = threadIdx.x;
  if (t < 8) ws[SBM + 16 * t] = 0u;
  if (t == 8) ws[CNT] = 0u;
  if (t < 32) {
    ws[BMM + 32 * t]      = 0xFFFFFFFFu;
    ws[BMM + 32 * t + 16] = 0u;
  }
}

// K1: folds only. Per quad-pair p: 8 threefry folds -> (a) per-subband bit-minmax acc,
//     (b) raw bits staged into `out` as two float4 stores at final pixel addresses.
//     Block tail: 8 atomicMax to dedicated 64B lines; LAST block (atomic ticket) also
//     derives the 4 subband scales — __syncthreads drains vmcnt, so every block's
//     atomicMax is globally performed before its ticket increments.
__global__ __launch_bounds__(256) void k_bits(float* __restrict__ out,
                                              uint32_t* __restrict__ ws) {
  const int tid = threadIdx.x;
  uint32_t p = (uint32_t)blockIdx.x * (PPT * 256u) + (uint32_t)tid;
  size_t base = (size_t)(p >> 7) * 1024u + 4u * (size_t)(p & 127u);
  uint32_t acc[8];   // {bmax_s, ~bmin_s} pairs, reduce-all-with-max
  #pragma unroll
  for (int r = 0; r < 8; ++r) acc[r] = 0u;
  #pragma unroll 2
  for (int k = 0; k < PPT; ++k) {
    const uint32_t qa = 2u * p, qb = 2u * p + 1u;
    const uint32_t a0 = tf_fold(SK0.x, SK0.y, qa);
    const uint32_t a1 = tf_fold(SK1.x, SK1.y, qa);
    const uint32_t a2 = tf_fold(SK2.x, SK2.y, qa);
    const uint32_t a3 = tf_fold(SK3.x, SK3.y, qa);
    const uint32_t b0 = tf_fold(SK0.x, SK0.y, qb);
    const uint32_t b1 = tf_fold(SK1.x, SK1.y, qb);
    const uint32_t b2 = tf_fold(SK2.x, SK2.y, qb);
    const uint32_t b3 = tf_fold(SK3.x, SK3.y, qb);
    acc[0] = max(acc[0], max(a0, b0)); acc[1] = max(acc[1], max(~a0, ~b0));
    acc[2] = max(acc[2], max(a1, b1)); acc[3] = max(acc[3], max(~a1, ~b1));
    acc[4] = max(acc[4], max(a2, b2)); acc[5] = max(acc[5], max(~a2, ~b2));
    acc[6] = max(acc[6], max(a3, b3)); acc[7] = max(acc[7], max(~a3, ~b3));
    *(float4*)(out + base) = make_float4(__uint_as_float(a0), __uint_as_float(a1),
                                         __uint_as_float(b0), __uint_as_float(b1));
    *(float4*)(out + base + 512) = make_float4(__uint_as_float(a2), __uint_as_float(a3),
                                               __uint_as_float(b2), __uint_as_float(b3));
    p += 256u;        // strength-reduced: row += 2 per step
    base += 2048u;
  }
  #pragma unroll
  for (int off = 32; off > 0; off >>= 1) {
    #pragma unroll
    for (int r = 0; r < 8; ++r)
      acc[r] = max(acc[r], (uint32_t)__shfl_down(acc[r], off));
  }
  __shared__ uint32_t sU[32];
  __shared__ uint32_t sLast;
  const int lane = tid & 63, w = tid >> 6;
  if (lane == 0) {
    #pragma unroll
    for (int r = 0; r < 8; ++r) sU[w * 8 + r] = acc[r];
  }
  __syncthreads();
  if (tid < 8) {
    uint32_t v = max(max(sU[tid], sU[8 + tid]), max(sU[16 + tid], sU[24 + tid]));
    atomicMax(&ws[SBM + 16 * tid], v);
  }
  __syncthreads();                 // drains vmcnt: this block's atomicMax now globally performed
  if (tid == 0) sLast = (atomicAdd(&ws[CNT], 1u) == (uint32_t)(NBK - 1)) ? 1u : 0u;
  __syncthreads();
  if (sLast) {                     // block-uniform branch
    if (tid < 8) sU[tid] = atomicMax(&ws[SBM + 16 * tid], 0u);   // coherent read of final value
    __syncthreads();
    if (tid < 4) {
      const uint32_t bmax = sU[2 * tid], bmin = ~sU[2 * tid + 1];
      const float nmax = normal_precise(bmax);
      const float nmin = normal_precise(bmin);
      const float mabs = fmaxf(nmax, -nmin);
      // 0.5 (idwt) and sqrt2 (normal_core omits it) folded in; 0.5 mult is exact.
      ((float*)ws)[SC + tid] = 0.5f * (1.41421354f / (mabs + 1e-8f));
    }
  }
}

// K2: enc = img + idwt(scaled erfinv(bits)); 4 quads/thread (2 col-groups x 1 row-pair),
//     all 8 float4 loads issued before compute. Preamble = 4 uniform float loads.
//     Reads staged bits from `out`, writes enc to the SAME addresses (thread-private).
__global__ __launch_bounds__(256) void k_enc(const float* __restrict__ img,
                                             float* __restrict__ out,
                                             uint32_t* __restrict__ ws) {
  const int tid = threadIdx.x;
  const float* wsf = (const float*)ws;
  const float s0 = wsf[SC + 0], s1 = wsf[SC + 1], s2 = wsf[SC + 2], s3 = wsf[SC + 3];

  const int rp = tid >> 6;                      // row-pair within block 0..3
  const int c  = tid & 63;                      // col group (float4 index, of 128)
  const int qi = blockIdx.x * 4 + rp;           // quad row 0..255
  const int bc = blockIdx.z * 3 + blockIdx.y;
  const size_t base = ((size_t)bc * 512 + 2 * qi) * 512 + 4 * c;
  // 8 loads up front (bits from out, pixels from img) — max MLP
  const float4 btA = *(const float4*)(out + base);
  const float4 bbA = *(const float4*)(out + base + 512);
  const float4 btB = *(const float4*)(out + base + 256);
  const float4 bbB = *(const float4*)(out + base + 768);
  const float4 itA = *(const float4*)(img + base);
  const float4 ibA = *(const float4*)(img + base + 512);
  const float4 itB = *(const float4*)(img + base + 256);
  const float4 ibB = *(const float4*)(img + base + 768);

  float vmin, vmax;
  float4 et, eb;
  // ---- group A ----
  {
    float n0 = normal_core(__float_as_uint(btA.x)) * s0;
    float n1 = normal_core(__float_as_uint(btA.y)) * s1;
    float n2 = normal_core(__float_as_uint(bbA.x)) * s2;
    float n3 = normal_core(__float_as_uint(bbA.y)) * s3;
    et.x = itA.x + (n0 + n1 + n2 + n3);
    et.y = itA.y + (n0 + n1 - n2 - n3);
    eb.x = ibA.x + (n0 - n1 + n2 - n3);
    eb.y = ibA.y + (n0 - n1 - n2 + n3);
    n0 = normal_core(__float_as_uint(btA.z)) * s0;
    n1 = normal_core(__float_as_uint(btA.w)) * s1;
    n2 = normal_core(__float_as_uint(bbA.z)) * s2;
    n3 = normal_core(__float_as_uint(bbA.w)) * s3;
    et.z = itA.z + (n0 + n1 + n2 + n3);
    et.w = itA.w + (n0 + n1 - n2 - n3);
    eb.z = ibA.z + (n0 - n1 + n2 - n3);
    eb.w = ibA.w + (n0 - n1 - n2 + n3);
    *(float4*)(out + base)       = et;
    *(float4*)(out + base + 512) = eb;
    vmin = fminf(fminf(fminf(et.x, et.y), fminf(et.z, et.w)),
                 fminf(fminf(eb.x, eb.y), fminf(eb.z, eb.w)));
    vmax = fmaxf(fmaxf(fmaxf(et.x, et.y), fmaxf(et.z, et.w)),
                 fmaxf(fmaxf(eb.x, eb.y), fmaxf(eb.z, eb.w)));
  }
  // ---- group B ----
  {
    float n0 = normal_core(__float_as_uint(btB.x)) * s0;
    float n1 = normal_core(__float_as_uint(btB.y)) * s1;
    float n2 = normal_core(__float_as_uint(bbB.x)) * s2;
    float n3 = normal_core(__float_as_uint(bbB.y)) * s3;
    et.x = itB.x + (n0 + n1 + n2 + n3);
    et.y = itB.y + (n0 + n1 - n2 - n3);
    eb.x = ibB.x + (n0 - n1 + n2 - n3);
    eb.y = ibB.y + (n0 - n1 - n2 + n3);
    n0 = normal_core(__float_as_uint(btB.z)) * s0;
    n1 = normal_core(__float_as_uint(btB.w)) * s1;
    n2 = normal_core(__float_as_uint(bbB.z)) * s2;
    n3 = normal_core(__float_as_uint(bbB.w)) * s3;
    et.z = itB.z + (n0 + n1 + n2 + n3);
    et.w = itB.w + (n0 + n1 - n2 - n3);
    eb.z = ibB.z + (n0 - n1 + n2 - n3);
    eb.w = ibB.w + (n0 - n1 - n2 + n3);
    *(float4*)(out + base + 256) = et;
    *(float4*)(out + base + 768) = eb;
    vmin = fminf(vmin, fminf(fminf(fminf(et.x, et.y), fminf(et.z, et.w)),
                             fminf(fminf(eb.x, eb.y), fminf(eb.z, eb.w))));
    vmax = fmaxf(vmax, fmaxf(fmaxf(fmaxf(et.x, et.y), fmaxf(et.z, et.w)),
                             fmaxf(fmaxf(eb.x, eb.y), fmaxf(eb.z, eb.w))));
  }
  #pragma unroll
  for (int off = 32; off > 0; off >>= 1) {
    vmin = fminf(vmin, __shfl_down(vmin, off));
    vmax = fmaxf(vmax, __shfl_down(vmax, off));
  }
  __shared__ float smin[4], smax[4];
  const int lane = tid & 63, w = tid >> 6;
  if (lane == 0) { smin[w] = vmin; smax[w] = vmax; }
  __syncthreads();
  if (tid == 0) {
    vmin = fminf(fminf(smin[0], smin[1]), fminf(smin[2], smin[3]));
    vmax = fmaxf(fmaxf(smax[0], smax[1]), fmaxf(smax[2], smax[3]));
    atomicMin(&ws[BMM + 32 * blockIdx.z], map_ord(vmin));
    atomicMax(&ws[BMM + 32 * blockIdx.z + 16], map_ord(vmax));
  }
}

// K3: in-place per-batch min-max normalize; block-uniform batch, 4 float4/thread.
__global__ __launch_bounds__(256) void k_norm(float* __restrict__ out,
                                              const uint32_t* __restrict__ ws) {
  const int bx = blockIdx.x;
  const int b = bx / (196608 / NORM_B4);        // 192 blocks per batch, uniform
  const float mn = unmap_ord(ws[BMM + 32 * b]);
  const float mx = unmap_ord(ws[BMM + 32 * b + 16]);
  const float inv = 1.0f / fmaxf(mx - mn, 1e-8f);
  float4* o4 = (float4*)out;
  const int i0 = bx * NORM_B4 + threadIdx.x;
  float4 v0 = o4[i0];
  float4 v1 = o4[i0 + 256];
  float4 v2 = o4[i0 + 512];
  float4 v3 = o4[i0 + 768];
  v0.x = (v0.x - mn) * inv; v0.y = (v0.y - mn) * inv;
  v0.z = (v0.z - mn) * inv; v0.w = (v0.w - mn) * inv;
  v1.x = (v1.x - mn) * inv; v1.y = (v1.y - mn) * inv;
  v1.z = (v1.z - mn) * inv; v1.w = (v1.w - mn) * inv;
  v2.x = (v2.x - mn) * inv; v2.y = (v2.y - mn) * inv;
  v2.z = (v2.z - mn) * inv; v2.w = (v2.w - mn) * inv;
  v3.x = (v3.x - mn) * inv; v3.y = (v3.y - mn) * inv;
  v3.z = (v3.z - mn) * inv; v3.w = (v3.w - mn) * inv;
  o4[i0]       = v0;
  o4[i0 + 256] = v1;
  o4[i0 + 512] = v2;
  o4[i0 + 768] = v3;
}

extern "C" void kernel_launch(void* const* d_in, const int* in_sizes, int n_in,
                              void* d_out, int out_size, void* d_ws, size_t ws_size,
                              hipStream_t stream) {
  const float* img = (const float*)d_in[0];
  float* out = (float*)d_out;
  uint32_t* ws = (uint32_t*)d_ws;

  k_init<<<1, 64, 0, stream>>>(ws);
  k_bits<<<NBK, 256, 0, stream>>>(out, ws);
  k_enc<<<dim3(64, 3, 32), 256, 0, stream>>>(img, out, ws);
  k_norm<<<NSUB / NORM_B4, 256, 0, stream>>>(out, ws);
}